// Round 13
// baseline (124.266 us; speedup 1.0000x reference)
//
#include <hip/hip_runtime.h>
#include <hip/hip_bf16.h>

typedef float f32x4 __attribute__((ext_vector_type(4)));
typedef __bf16 bf16x8 __attribute__((ext_vector_type(8)));
typedef unsigned short ushort8 __attribute__((ext_vector_type(8)));

#define SEQ 2048
#define LOG2E 1.4426950408889634f

__device__ __forceinline__ unsigned short f2bf(float f) {
    unsigned int u = __builtin_bit_cast(unsigned int, f);
    unsigned int r = (u + 0x7FFFu + ((u >> 16) & 1u)) >> 16;
    return (unsigned short)r;
}

__device__ __forceinline__ void gload_lds16(const unsigned short* g, unsigned short* l) {
    __builtin_amdgcn_global_load_lds(
        (const __attribute__((address_space(1))) unsigned int*)g,
        (__attribute__((address_space(3))) unsigned int*)l, 16, 0, 0);
}

// ---------------------------------------------------------------------------
// fp32 -> bf16 bulk convert. seg 0: query (4096x1024); seg 1..4: weights.
// ---------------------------------------------------------------------------
__global__ __launch_bounds__(256) void conv_bf16(
    const float* __restrict__ s0, const float* __restrict__ s1,
    const float* __restrict__ s2, const float* __restrict__ s3,
    const float* __restrict__ s4,
    unsigned short* __restrict__ d0, unsigned short* __restrict__ d1,
    unsigned short* __restrict__ d2, unsigned short* __restrict__ d3,
    unsigned short* __restrict__ d4)
{
    const int seg = blockIdx.y;
    const float* s = seg == 0 ? s0 : seg == 1 ? s1 : seg == 2 ? s2 : seg == 3 ? s3 : s4;
    unsigned short* d = seg == 0 ? d0 : seg == 1 ? d1 : seg == 2 ? d2 : seg == 3 ? d3 : d4;
    const int n = seg == 0 ? (4096 * 1024) : (1024 * 1024);
    const int i = (blockIdx.x * 256 + threadIdx.x) * 8;
    if (i >= n) return;
    float4 a = *(const float4*)(s + i);
    float4 b = *(const float4*)(s + i + 4);
    ushort8 o;
    o[0] = f2bf(a.x); o[1] = f2bf(a.y); o[2] = f2bf(a.z); o[3] = f2bf(a.w);
    o[4] = f2bf(b.x); o[5] = f2bf(b.y); o[6] = f2bf(b.z); o[7] = f2bf(b.w);
    *(ushort8*)(d + i) = o;
}

// ---------------------------------------------------------------------------
// bf16 GEMM: C[M,N] = A[M,K] * W[N,K]^T + bias. M=4096, N=K=1024.
// 128x128 tile, 256 threads (4 waves, 2x2 of 64x64).
// R13: BK=32 + R10's verified __syncthreads double-buffer ->
//   LDS 32 KiB -> 5 blocks/CU (20 waves, was 2 blocks/8 waves at BK=64).
//   Mechanism: the per-iter barrier drain is now covered by 4 OTHER resident
//   blocks' work instead of being exposed (R11's BK=32 failure was counted-
//   vmcnt at 2 blocks/CU: double barriers, no extra TLP. This combo takes
//   R11's verified staging arithmetic + R10's verified sync structure.)
// Staging (BK=32, R11-verbatim): chunk = 16 rows x 32 cols; lane:
//   row=ch*16+(lane>>2), dest slot=lane&3; source slot pre-XOR'd by
//   ((lane>>3)&3) == (row>>1)&3; read slot = lhi ^ ((l15>>1)&3) -> 2-way
//   bank aliasing (free, m136).
// bm-major grid (32,8,3): id%8 == bm%8 (A-tile read by ONE XCD, R10).
// Epilogue modes: 0=q LN bf16 (*0.125*log2e), 1=k LN bf16 (d-chunk XOR s&7),
//                 2=v^T bf16 [B,H,64,S] (key-perm pi + s-chunk XOR by d&7),
//                 3=fp32 [M,N] (unused).
// ---------------------------------------------------------------------------
__global__ __launch_bounds__(256) void gemm_bf16(
    const unsigned short* __restrict__ A,
    const unsigned short* __restrict__ W0, const unsigned short* __restrict__ W1,
    const unsigned short* __restrict__ W2,
    const float* __restrict__ b0, const float* __restrict__ b1, const float* __restrict__ b2,
    const float* __restrict__ ln_g0, const float* __restrict__ ln_b0,
    const float* __restrict__ ln_g1, const float* __restrict__ ln_b1,
    unsigned short* __restrict__ qn, unsigned short* __restrict__ kn,
    unsigned short* __restrict__ vt,
    float* __restrict__ Cout, int fixed_mode)
{
    const int z = fixed_mode < 0 ? (int)blockIdx.z : fixed_mode;
    const unsigned short* W = (z == 1) ? W1 : (z == 2) ? W2 : W0;
    const float* bias = (z == 1) ? b1 : (z == 2) ? b2 : b0;

    const int bm = blockIdx.x * 128;    // bm-major: id%8 == bm-tile%8
    const int bn = blockIdx.y * 128;

    __shared__ unsigned short As[2][128 * 32];   // 2 x 8 KiB
    __shared__ unsigned short Bs[2][128 * 32];   // 2 x 8 KiB

    const int t    = threadIdx.x;
    const int lane = t & 63;
    const int wid  = t >> 6;
    const int l15  = lane & 15;
    const int lhi  = lane >> 4;
    const int wm   = (wid >> 1) * 64;
    const int wn   = (wid & 1) * 64;

    // staging lane map (R11-verified): row = ch*16 + (lane>>2), dest slot =
    // lane&3, source slot pre-XOR'd so linear LDS image is swizzled
    const int schunk = (lane & 3) ^ ((lane >> 3) & 3);
    const unsigned short* Ag = A + (size_t)(bm + (lane >> 2)) * 1024 + schunk * 8;
    const unsigned short* Wg = W + (size_t)(bn + (lane >> 2)) * 1024 + schunk * 8;

    f32x4 acc[4][4];
#pragma unroll
    for (int i = 0; i < 4; ++i)
#pragma unroll
        for (int j = 0; j < 4; ++j) acc[i][j] = (f32x4)0.f;

    const int rslot = (lhi ^ ((l15 >> 1) & 3)) * 8;   // read slot (swizzled)

    // prologue: stage tile 0 into buf 0 (2 A + 2 W gloads per wave)
#pragma unroll
    for (int c = 0; c < 2; ++c) {
        const int ch = wid * 2 + c;
        gload_lds16(Ag + (size_t)ch * 16 * 1024, &As[0][ch * 512]);
        gload_lds16(Wg + (size_t)ch * 16 * 1024, &Bs[0][ch * 512]);
    }

#pragma unroll 4
    for (int it = 0; it < 32; ++it) {
        __syncthreads();                      // tile it staged everywhere
        if (it < 31) {                        // issue tile it+1 into other buf
            const int kt = (it + 1) * 32;
#pragma unroll
            for (int c = 0; c < 2; ++c) {
                const int ch = wid * 2 + c;
                gload_lds16(Ag + (size_t)ch * 16 * 1024 + kt, &As[(it + 1) & 1][ch * 512]);
                gload_lds16(Wg + (size_t)ch * 16 * 1024 + kt, &Bs[(it + 1) & 1][ch * 512]);
            }
        }
        const unsigned short* Ab = &As[it & 1][0];
        const unsigned short* Bb = &Bs[it & 1][0];
        bf16x8 af[4], bw[4];
#pragma unroll
        for (int mi = 0; mi < 4; ++mi)
            af[mi] = __builtin_bit_cast(bf16x8,
                *(const ushort8*)(&Ab[(wm + mi * 16 + l15) * 32 + rslot]));
#pragma unroll
        for (int ni = 0; ni < 4; ++ni)
            bw[ni] = __builtin_bit_cast(bf16x8,
                *(const ushort8*)(&Bb[(wn + ni * 16 + l15) * 32 + rslot]));
#pragma unroll
        for (int mi = 0; mi < 4; ++mi)
#pragma unroll
            for (int ni = 0; ni < 4; ++ni)
                acc[mi][ni] = __builtin_amdgcn_mfma_f32_16x16x32_bf16(af[mi], bw[ni], acc[mi][ni], 0, 0, 0);
    }
    __syncthreads();   // LDS reusable for epilogue staging

    if (z == 3) {
#pragma unroll
        for (int ni = 0; ni < 4; ++ni) {
            const int col = bn + wn + ni * 16 + l15;
            const float bv = bias[col];
#pragma unroll
            for (int mi = 0; mi < 4; ++mi) {
                const int row = bm + wm + mi * 16 + lhi * 4;
#pragma unroll
                for (int r = 0; r < 4; ++r)
                    Cout[(size_t)(row + r) * 1024 + col] = acc[mi][ni][r] + bv;
            }
        }
        return;
    }

    // 4 wave-scratch regions of 4096 shorts: As = 8192 shorts (2), Bs = 8192 (2)
    unsigned short* stg = ((wid & 2) ? &Bs[0][0] : &As[0][0]) + (wid & 1) * 4096;
    const int h = (bn + wn) >> 6;

    if (z == 2) {
        // V^T with key-perm pi: sl -> 32*(mi>>1) + lhi*8 + 2r + (mi&1),
        // then s-chunk XOR by (d&7) at store.
        float biasv[4];
#pragma unroll
        for (int ni = 0; ni < 4; ++ni) biasv[ni] = bias[bn + wn + ni * 16 + l15];
#pragma unroll
        for (int mi = 0; mi < 4; ++mi)
#pragma unroll
            for (int ni = 0; ni < 4; ++ni)
#pragma unroll
                for (int r = 0; r < 4; ++r)
                    stg[(ni * 16 + l15) * 64 + 32 * (mi >> 1) + lhi * 8 + 2 * r + (mi & 1)] =
                        f2bf(acc[mi][ni][r] + biasv[ni]);
        __builtin_amdgcn_s_waitcnt(0);
        const int srow0 = bm + wm;
        const int b = srow0 >> 11, sbase = srow0 & 2047;
#pragma unroll
        for (int i = 0; i < 8; ++i) {
            const int dl = i * 8 + (lane >> 3);
            const ushort8 v = *(const ushort8*)(&stg[dl * 64 + (((lane & 7) ^ (dl & 7)) * 8)]);
            *(ushort8*)(&vt[((size_t)((b * 16 + h) * 64 + dl)) * 2048 + sbase + (lane & 7) * 8]) = v;
        }
        return;
    }

    // z == 0/1: per-head LayerNorm over the wave's 64 cols (one head)
    const float* g  = (z == 0) ? ln_g0 : ln_g1;
    const float* bb = (z == 0) ? ln_b0 : ln_b1;
    unsigned short* outp = (z == 0) ? qn : kn;
    const float scale = (z == 0) ? 0.125f * LOG2E : 1.0f;
    const int sxor = (z == 1) ? 7 : 0;   // K global gets d-chunk XOR by (s&7)
    float gv[4], bbv[4], biasv[4];
#pragma unroll
    for (int ni = 0; ni < 4; ++ni) {
        const int d = ni * 16 + l15;
        gv[ni] = g[d]; bbv[ni] = bb[d]; biasv[ni] = bias[bn + wn + d];
    }
#pragma unroll
    for (int mi = 0; mi < 4; ++mi) {
#pragma unroll
        for (int r = 0; r < 4; ++r) {
            float x0 = acc[mi][0][r] + biasv[0];
            float x1 = acc[mi][1][r] + biasv[1];
            float x2 = acc[mi][2][r] + biasv[2];
            float x3 = acc[mi][3][r] + biasv[3];
            float sum = (x0 + x1) + (x2 + x3);
#pragma unroll
            for (int off = 1; off < 16; off <<= 1) sum += __shfl_xor(sum, off);
            const float mean = sum * (1.f / 64.f);
            const float d0 = x0 - mean, d1 = x1 - mean, d2 = x2 - mean, d3 = x3 - mean;
            float vs = (d0 * d0 + d1 * d1) + (d2 * d2 + d3 * d3);
#pragma unroll
            for (int off = 1; off < 16; off <<= 1) vs += __shfl_xor(vs, off);
            const float rstd = rsqrtf(vs * (1.f / 64.f) + 1e-5f);
            const int rl = mi * 16 + lhi * 4 + r;
            stg[rl * 64 +  0 + l15] = f2bf((d0 * rstd * gv[0] + bbv[0]) * scale);
            stg[rl * 64 + 16 + l15] = f2bf((d1 * rstd * gv[1] + bbv[1]) * scale);
            stg[rl * 64 + 32 + l15] = f2bf((d2 * rstd * gv[2] + bbv[2]) * scale);
            stg[rl * 64 + 48 + l15] = f2bf((d3 * rstd * gv[3] + bbv[3]) * scale);
        }
    }
    __builtin_amdgcn_s_waitcnt(0);
#pragma unroll
    for (int i = 0; i < 8; ++i) {
        const int rl  = i * 8 + (lane >> 3);
        const int srow = bm + wm + rl;
        const int b = srow >> 11, s = srow & 2047;
        const ushort8 v = *(const ushort8*)(&stg[rl * 64 + (((lane & 7) ^ (rl & sxor)) * 8)]);
        *(ushort8*)(&outp[((size_t)((b * 16 + h) * 2048 + s)) * 64 + (lane & 7) * 8]) = v;
    }
}

// ---------------------------------------------------------------------------
// Output-projection GEMM: C[M,N] = A[M,K] * W[N,K]^T + bias, fp32 out.
// BM=64, BN=128 (verified R8). Grid (64,8) x-major: 512 blocks, id%8 ==
// m-tile%8 keeps per-XCD A-slice + W L2-resident.
// R10-verbatim __syncthreads double-buffer pipeline. LDS 48 KiB.
// ---------------------------------------------------------------------------
__global__ __launch_bounds__(256) void gemm_out(
    const unsigned short* __restrict__ A,
    const unsigned short* __restrict__ W,
    const float* __restrict__ bias,
    float* __restrict__ Cout)
{
    const int bm = blockIdx.x * 64;
    const int bn = blockIdx.y * 128;

    __shared__ unsigned short As[2][64 * 64];
    __shared__ unsigned short Bs[2][128 * 64];

    const int t    = threadIdx.x;
    const int lane = t & 63;
    const int wid  = t >> 6;
    const int l15  = lane & 15;
    const int lhi  = lane >> 4;
    const int wm   = (wid >> 1) * 32;
    const int wn   = (wid & 1) * 64;

    const int schunk = (lane & 7) ^ ((lane >> 3) & 7);
    const unsigned short* Ag = A + (size_t)(bm + (lane >> 3)) * 1024 + schunk * 8;
    const unsigned short* Wg = W + (size_t)(bn + (lane >> 3)) * 1024 + schunk * 8;

    f32x4 acc[2][4];
#pragma unroll
    for (int i = 0; i < 2; ++i)
#pragma unroll
        for (int j = 0; j < 4; ++j) acc[i][j] = (f32x4)0.f;

    // prologue: stage tile 0 into buf 0
#pragma unroll
    for (int c = 0; c < 2; ++c) {
        const int ch = wid * 2 + c;
        gload_lds16(Ag + (size_t)ch * 8 * 1024, &As[0][ch * 512]);
    }
#pragma unroll
    for (int c = 0; c < 4; ++c) {
        const int ch = wid * 4 + c;
        gload_lds16(Wg + (size_t)ch * 8 * 1024, &Bs[0][ch * 512]);
    }

#pragma unroll 2
    for (int it = 0; it < 16; ++it) {
        __syncthreads();                      // tile it staged everywhere
        if (it < 15) {
            const int kt = (it + 1) * 64;
#pragma unroll
            for (int c = 0; c < 2; ++c) {
                const int ch = wid * 2 + c;
                gload_lds16(Ag + (size_t)ch * 8 * 1024 + kt, &As[(it + 1) & 1][ch * 512]);
            }
#pragma unroll
            for (int c = 0; c < 4; ++c) {
                const int ch = wid * 4 + c;
                gload_lds16(Wg + (size_t)ch * 8 * 1024 + kt, &Bs[(it + 1) & 1][ch * 512]);
            }
        }
        const unsigned short* Ab = &As[it & 1][0];
        const unsigned short* Bb = &Bs[it & 1][0];
#pragma unroll
        for (int kk = 0; kk < 2; ++kk) {
            const int rchunk = ((kk * 4 + lhi) ^ (l15 & 7)) * 8;
            bf16x8 af[2], bw[4];
#pragma unroll
            for (int mi = 0; mi < 2; ++mi)
                af[mi] = __builtin_bit_cast(bf16x8,
                    *(const ushort8*)(&Ab[(wm + mi * 16 + l15) * 64 + rchunk]));
#pragma unroll
            for (int ni = 0; ni < 4; ++ni)
                bw[ni] = __builtin_bit_cast(bf16x8,
                    *(const ushort8*)(&Bb[(wn + ni * 16 + l15) * 64 + rchunk]));
#pragma unroll
            for (int mi = 0; mi < 2; ++mi)
#pragma unroll
                for (int ni = 0; ni < 4; ++ni)
                    acc[mi][ni] = __builtin_amdgcn_mfma_f32_16x16x32_bf16(af[mi], bw[ni], acc[mi][ni], 0, 0, 0);
        }
    }

#pragma unroll
    for (int ni = 0; ni < 4; ++ni) {
        const int col = bn + wn + ni * 16 + l15;
        const float bv = bias[col];
#pragma unroll
        for (int mi = 0; mi < 2; ++mi) {
            const int row = bm + wm + mi * 16 + lhi * 4;
#pragma unroll
            for (int r = 0; r < 4; ++r)
                Cout[(size_t)(row + r) * 1024 + col] = acc[mi][ni][r] + bv;
        }
    }
}

// ---------------------------------------------------------------------------
// Flash attention. 128 q rows/block, 8 waves x 16 rows, KV tiles of 64.
// 4-buffer statically-indexed counted-vmcnt pipeline, ONE barrier per tile
// (harness-verified structure, R1/R4/R8-R12):
//   iter t: [DMA(t+2); SM(t); vmcnt(2)+barrier; QK(t+1); PV(t)]
// Grid is (bh, qblock) so linear id%8 == bh%8: all 16 q-blocks of a head land
// on one XCD -> K/V (512KB/head, 4 heads/XCD = 2MB) stays L2-resident.
// Softmax sub folded into MFMA C-init: sacc = mfma(a,b, mneg).
// ---------------------------------------------------------------------------
__global__ __launch_bounds__(512, 4) void attn(
    const unsigned short* __restrict__ qn, const unsigned short* __restrict__ kn,
    const unsigned short* __restrict__ vt, unsigned short* __restrict__ o)
{
    __shared__ unsigned short Ks[4][64 * 64];
    __shared__ unsigned short Vs[4][64 * 64];
    __shared__ unsigned short Ps[128 * 64];

    const int tid  = threadIdx.x;
    const int lane = tid & 63;
    const int w    = tid >> 6;
    const int l15  = lane & 15;
    const int lhi  = lane >> 4;

    const int bh = blockIdx.x;          // b*16 + h  (x-major -> same-head co-XCD)
    const int q0 = blockIdx.y * 128;

    const unsigned short* qrp = qn + ((size_t)bh * SEQ + q0 + w * 16 + l15) * 64 + lhi * 8;
    const bf16x8 aq0 = __builtin_bit_cast(bf16x8, *(const ushort8*)(qrp));
    const bf16x8 aq1 = __builtin_bit_cast(bf16x8, *(const ushort8*)(qrp + 32));

    // DMA staging: wave w covers rows w*8..w*8+7; lane: row w*8+(lane>>3), chunk lane&7
    const unsigned short* kg = kn + ((size_t)bh * SEQ + w * 8 + (lane >> 3)) * 64 + (lane & 7) * 8;
    const unsigned short* vg = vt + ((size_t)bh * 64 + w * 8 + (lane >> 3)) * 2048 + (lane & 7) * 8;

    f32x4 oacc[4];
#pragma unroll
    for (int nd = 0; nd < 4; ++nd) oacc[nd] = (f32x4)0.f;
    float l_part[4];
#pragma unroll
    for (int i = 0; i < 4; ++i) l_part[i] = 0.f;
    f32x4 mneg = (f32x4)100.f;          // -m_run; m_run starts at -100 (finite)

    f32x4 sacc[4];

    auto QK = [&](const unsigned short* kb) {
        __builtin_amdgcn_s_setprio(1);
#pragma unroll
        for (int ni = 0; ni < 4; ++ni) {
            const int krow = ni * 16 + l15;
            const bf16x8 bk = __builtin_bit_cast(bf16x8,
                *(const ushort8*)(&kb[krow * 64 + ((lhi ^ (krow & 7)) * 8)]));
            sacc[ni] = __builtin_amdgcn_mfma_f32_16x16x32_bf16(aq0, bk, mneg, 0, 0, 0);
        }
#pragma unroll
        for (int ni = 0; ni < 4; ++ni) {
            const int krow = ni * 16 + l15;
            const bf16x8 bk = __builtin_bit_cast(bf16x8,
                *(const ushort8*)(&kb[krow * 64 + (((4 + lhi) ^ (krow & 7)) * 8)]));
            sacc[ni] = __builtin_amdgcn_mfma_f32_16x16x32_bf16(aq1, bk, sacc[ni], 0, 0, 0);
        }
        __builtin_amdgcn_s_setprio(0);
    };

    // prologue: stage tiles 0 and 1, wait tile 0, compute QK(0)
    gload_lds16(kg,                    &Ks[0][w * 512]);
    gload_lds16(vg,                    &Vs[0][w * 512]);
    gload_lds16(kg + (size_t)64 * 64,  &Ks[1][w * 512]);
    gload_lds16(vg + 64,               &Vs[1][w * 512]);
    __builtin_amdgcn_sched_barrier(0);
    asm volatile("s_waitcnt vmcnt(2)" ::: "memory");
    asm volatile("s_barrier" ::: "memory");
    QK(&Ks[0][0]);

#pragma unroll 4
    for (int t = 0; t < 32; ++t) {
        // issue DMA for tile t+2 into buf (t+2)&3 (statically indexed)
        if (t < 30) {
            gload_lds16(kg + (size_t)(t + 2) * 64 * 64, &Ks[(t + 2) & 3][w * 512]);
            gload_lds16(vg + (t + 2) * 64,              &Vs[(t + 2) & 3][w * 512]);
        }
        __builtin_amdgcn_sched_barrier(0);

        // SM(t): sacc already holds s - m_run (C-init bias); defer-max softmax
        float tmax[4];
#pragma unroll
        for (int r = 0; r < 4; ++r)
            tmax[r] = fmaxf(fmaxf(fmaxf(sacc[0][r], sacc[1][r]), sacc[2][r]), sacc[3][r]);
        const float dmax = fmaxf(fmaxf(fmaxf(tmax[0], tmax[1]), tmax[2]), tmax[3]);
        if (!__all(dmax <= 8.0f)) {          // rare: rescale path
#pragma unroll
            for (int r = 0; r < 4; ++r) {
                float tm = tmax[r];
#pragma unroll
                for (int off = 1; off < 16; off <<= 1) tm = fmaxf(tm, __shfl_xor(tm, off));
                const float delta = fmaxf(tm, 0.f);      // m_new - m_old
                const float alpha = __builtin_amdgcn_exp2f(-delta);
                mneg[r] -= delta;
                l_part[r] *= alpha;
#pragma unroll
                for (int nd = 0; nd < 4; ++nd) oacc[nd][r] *= alpha;
#pragma unroll
                for (int ni = 0; ni < 4; ++ni) sacc[ni][r] -= delta;
            }
        }
#pragma unroll
        for (int r = 0; r < 4; ++r) {
            const float p0 = __builtin_amdgcn_exp2f(sacc[0][r]);
            const float p1 = __builtin_amdgcn_exp2f(sacc[1][r]);
            const float p2 = __builtin_amdgcn_exp2f(sacc[2][r]);
            const float p3 = __builtin_amdgcn_exp2f(sacc[3][r]);
            l_part[r] += (p0 + p1) + (p2 + p3);
            unsigned int pk0, pk1;
            asm("v_cvt_pk_bf16_f32 %0, %1, %2" : "=v"(pk0) : "v"(p0), "v"(p1));
            asm("v_cvt_pk_bf16_f32 %0, %1, %2" : "=v"(pk1) : "v"(p2), "v"(p3));
            const int prow = w * 16 + lhi * 4 + r;
            const int rs7  = prow & 7;
            *(unsigned int*)(&Ps[prow * 64 + (((l15 >> 2) ^ rs7) * 8) + 2 * (l15 & 3)]) = pk0;
            *(unsigned int*)(&Ps[prow * 64 + (((4 + (l15 >> 2)) ^ rs7) * 8) + 2 * (l15 & 3)]) = pk1;
        }

        // QK(t+1): hoisted between Ps writes and Ps reads (single barrier/tile)
        if (t < 31) {
            if (t < 30) { asm volatile("s_waitcnt vmcnt(2)" ::: "memory"); }
            else        { asm volatile("s_waitcnt vmcnt(0)" ::: "memory"); }
            asm volatile("s_barrier" ::: "memory");   // tile t+1 staged everywhere
            QK(&Ks[(t + 1) & 3][0]);
        }

        // PV(t)
        __builtin_amdgcn_s_setprio(1);
#pragma unroll
        for (int kk = 0; kk < 2; ++kk) {
            const int arow = w * 16 + l15;
            const bf16x8 ap = __builtin_bit_cast(bf16x8,
                *(const ushort8*)(&Ps[arow * 64 + (((kk * 4 + lhi) ^ (arow & 7)) * 8)]));
#pragma unroll
            for (int nd = 0; nd < 4; ++nd) {
                const int vrow = nd * 16 + l15;
                const bf16x8 bv = __builtin_bit_cast(bf16x8,
                    *(const ushort8*)(&Vs[t & 3][vrow * 64 + (((kk * 4 + lhi) ^ (vrow & 7)) * 8)]));
                oacc[nd] = __builtin_amdgcn_mfma_f32_16x16x32_bf16(ap, bv, oacc[nd], 0, 0, 0);
            }
        }
        __builtin_amdgcn_s_setprio(0);
    }

    // epilogue: reduce l, O/l, bf16 out [B,S,H,64]
    const int b = bh >> 4, h = bh & 15;
#pragma unroll
    for (int r = 0; r < 4; ++r) {
        float ls = l_part[r];
#pragma unroll
        for (int off = 1; off < 16; off <<= 1) ls += __shfl_xor(ls, off);
        const float inv = 1.f / ls;
        const int qrow = q0 + w * 16 + lhi * 4 + r;
        const size_t base = ((size_t)(b * SEQ + qrow) * 16 + h) * 64;
#pragma unroll
        for (int nd = 0; nd < 4; ++nd)
            o[base + nd * 16 + l15] = f2bf(oacc[nd][r] * inv);
    }
}

// ---------------------------------------------------------------------------
extern "C" void kernel_launch(void* const* d_in, const int* in_sizes, int n_in,
                              void* d_out, int out_size, void* d_ws, size_t ws_size,
                              hipStream_t stream)
{
    const float* query  = (const float*)d_in[0];
    const float* q_w    = (const float*)d_in[1];
    const float* q_b    = (const float*)d_in[2];
    const float* k_w    = (const float*)d_in[3];
    const float* k_b    = (const float*)d_in[4];
    const float* v_w    = (const float*)d_in[5];
    const float* v_b    = (const float*)d_in[6];
    const float* o_w    = (const float*)d_in[7];
    const float* o_b    = (const float*)d_in[8];
    const float* q_ln_g = (const float*)d_in[9];
    const float* q_ln_b = (const float*)d_in[10];
    const float* k_ln_g = (const float*)d_in[11];
    const float* k_ln_b = (const float*)d_in[12];

    char* ws = (char*)d_ws;
    unsigned short* qbf = (unsigned short*)(ws);                   // 8 MB
    unsigned short* wq  = (unsigned short*)(ws + (8ull  << 20));   // 2 MB
    unsigned short* wk  = (unsigned short*)(ws + (10ull << 20));   // 2 MB
    unsigned short* wv  = (unsigned short*)(ws + (12ull << 20));   // 2 MB
    unsigned short* wo  = (unsigned short*)(ws + (14ull << 20));   // 2 MB
    unsigned short* qnb = (unsigned short*)(ws + (16ull << 20));   // 8 MB
    unsigned short* knb = (unsigned short*)(ws + (24ull << 20));   // 8 MB
    unsigned short* vtb = (unsigned short*)(ws + (32ull << 20));   // 8 MB
    unsigned short* ofb = (unsigned short*)(ws + (40ull << 20));   // 8 MB

    conv_bf16<<<dim3(2048, 5), 256, 0, stream>>>(query, q_w, k_w, v_w, o_w,
                                                 qbf, wq, wk, wv, wo);

    dim3 g1(32, 8, 3);
    gemm_bf16<<<g1, 256, 0, stream>>>(qbf, wq, wk, wv, q_b, k_b, v_b,
                                      q_ln_g, q_ln_b, k_ln_g, k_ln_b,
                                      qnb, knb, vtb, nullptr, -1);

    dim3 g3(32, 16);
    attn<<<g3, 512, 0, stream>>>(qnb, knb, vtb, ofb);

    dim3 g4(64, 8);
    gemm_out<<<g4, 256, 0, stream>>>(ofb, wo, o_b, (float*)d_out);
}

// Round 14
// 116.837 us; speedup vs baseline: 1.0636x; 1.0636x over previous
//
#include <hip/hip_runtime.h>
#include <hip/hip_bf16.h>

typedef float f32x4 __attribute__((ext_vector_type(4)));
typedef __bf16 bf16x8 __attribute__((ext_vector_type(8)));
typedef unsigned short ushort8 __attribute__((ext_vector_type(8)));

#define SEQ 2048
#define LOG2E 1.4426950408889634f

__device__ __forceinline__ unsigned short f2bf(float f) {
    unsigned int u = __builtin_bit_cast(unsigned int, f);
    unsigned int r = (u + 0x7FFFu + ((u >> 16) & 1u)) >> 16;
    return (unsigned short)r;
}

__device__ __forceinline__ void gload_lds16(const unsigned short* g, unsigned short* l) {
    __builtin_amdgcn_global_load_lds(
        (const __attribute__((address_space(1))) unsigned int*)g,
        (__attribute__((address_space(3))) unsigned int*)l, 16, 0, 0);
}

// ---------------------------------------------------------------------------
// fp32 -> bf16 bulk convert. seg 0: query (4096x1024); seg 1..4: weights.
// ---------------------------------------------------------------------------
__global__ __launch_bounds__(256) void conv_bf16(
    const float* __restrict__ s0, const float* __restrict__ s1,
    const float* __restrict__ s2, const float* __restrict__ s3,
    const float* __restrict__ s4,
    unsigned short* __restrict__ d0, unsigned short* __restrict__ d1,
    unsigned short* __restrict__ d2, unsigned short* __restrict__ d3,
    unsigned short* __restrict__ d4)
{
    const int seg = blockIdx.y;
    const float* s = seg == 0 ? s0 : seg == 1 ? s1 : seg == 2 ? s2 : seg == 3 ? s3 : s4;
    unsigned short* d = seg == 0 ? d0 : seg == 1 ? d1 : seg == 2 ? d2 : seg == 3 ? d3 : d4;
    const int n = seg == 0 ? (4096 * 1024) : (1024 * 1024);
    const int i = (blockIdx.x * 256 + threadIdx.x) * 8;
    if (i >= n) return;
    float4 a = *(const float4*)(s + i);
    float4 b = *(const float4*)(s + i + 4);
    ushort8 o;
    o[0] = f2bf(a.x); o[1] = f2bf(a.y); o[2] = f2bf(a.z); o[3] = f2bf(a.w);
    o[4] = f2bf(b.x); o[5] = f2bf(b.y); o[6] = f2bf(b.z); o[7] = f2bf(b.w);
    *(ushort8*)(d + i) = o;
}

// ---------------------------------------------------------------------------
// bf16 GEMM: C[M,N] = A[M,K] * W[N,K]^T + bias. M=4096, N=K=1024.
// 128x128 tile, BK=64, 256 threads (4 waves, 2x2 of 64x64).  [R10-verbatim:
// verified best. Bracket complete: R9 phase-offset=0, R11 counted-vmcnt
// BK=32 = -3.6us, R13 dbuf BK=32 5blk/CU = -6us. BK=64 dbuf wins.]
//  (1) DOUBLE-BUFFERED staging via __syncthreads 2-stage pipeline:
//      sync(tile t ready) -> issue DMA(t+1) -> compute(t).
//  (2) bm-major grid (32,8,3): id%8 == bm%8, A-tile read by ONE XCD.
// Epilogue modes: 0=q LN bf16 (*0.125*log2e), 1=k LN bf16 (d-chunk XOR by s&7),
//                 2=v^T bf16 [B,H,64,S] (key-perm pi + s-chunk XOR by d&7),
//                 3=fp32 [M,N] (unused; superseded by gemm_out).
// ---------------------------------------------------------------------------
__global__ __launch_bounds__(256) void gemm_bf16(
    const unsigned short* __restrict__ A,
    const unsigned short* __restrict__ W0, const unsigned short* __restrict__ W1,
    const unsigned short* __restrict__ W2,
    const float* __restrict__ b0, const float* __restrict__ b1, const float* __restrict__ b2,
    const float* __restrict__ ln_g0, const float* __restrict__ ln_b0,
    const float* __restrict__ ln_g1, const float* __restrict__ ln_b1,
    unsigned short* __restrict__ qn, unsigned short* __restrict__ kn,
    unsigned short* __restrict__ vt,
    float* __restrict__ Cout, int fixed_mode)
{
    const int z = fixed_mode < 0 ? (int)blockIdx.z : fixed_mode;
    const unsigned short* W = (z == 1) ? W1 : (z == 2) ? W2 : W0;
    const float* bias = (z == 1) ? b1 : (z == 2) ? b2 : b0;

    const int bm = blockIdx.x * 128;    // bm-major: id%8 == bm-tile%8
    const int bn = blockIdx.y * 128;

    __shared__ unsigned short As[2][128 * 64];
    __shared__ unsigned short Bs[2][128 * 64];

    const int t    = threadIdx.x;
    const int lane = t & 63;
    const int wid  = t >> 6;
    const int l15  = lane & 15;
    const int lhi  = lane >> 4;
    const int wm   = (wid >> 1) * 64;
    const int wn   = (wid & 1) * 64;

    // source chunk pre-permuted so linear LDS image is bank-swizzled
    const int schunk = (lane & 7) ^ ((lane >> 3) & 7);
    const unsigned short* Ag = A + (size_t)(bm + (lane >> 3)) * 1024 + schunk * 8;
    const unsigned short* Wg = W + (size_t)(bn + (lane >> 3)) * 1024 + schunk * 8;

    f32x4 acc[4][4];
#pragma unroll
    for (int i = 0; i < 4; ++i)
#pragma unroll
        for (int j = 0; j < 4; ++j) acc[i][j] = (f32x4)0.f;

    // prologue: stage tile 0 into buf 0
#pragma unroll
    for (int c = 0; c < 4; ++c) {
        const int ch = wid * 4 + c;
        gload_lds16(Ag + (size_t)ch * 8 * 1024, &As[0][ch * 512]);
        gload_lds16(Wg + (size_t)ch * 8 * 1024, &Bs[0][ch * 512]);
    }

#pragma unroll 2
    for (int it = 0; it < 16; ++it) {
        __syncthreads();                      // tile it staged everywhere
        if (it < 15) {                        // issue tile it+1 into other buf
            const int kt = (it + 1) * 64;
#pragma unroll
            for (int c = 0; c < 4; ++c) {
                const int ch = wid * 4 + c;
                gload_lds16(Ag + (size_t)ch * 8 * 1024 + kt, &As[(it + 1) & 1][ch * 512]);
                gload_lds16(Wg + (size_t)ch * 8 * 1024 + kt, &Bs[(it + 1) & 1][ch * 512]);
            }
        }
        const unsigned short* Ab = &As[it & 1][0];
        const unsigned short* Bb = &Bs[it & 1][0];
#pragma unroll
        for (int kk = 0; kk < 2; ++kk) {
            const int rchunk = ((kk * 4 + lhi) ^ (l15 & 7)) * 8;
            bf16x8 af[4], bw[4];
#pragma unroll
            for (int mi = 0; mi < 4; ++mi)
                af[mi] = __builtin_bit_cast(bf16x8,
                    *(const ushort8*)(&Ab[(wm + mi * 16 + l15) * 64 + rchunk]));
#pragma unroll
            for (int ni = 0; ni < 4; ++ni)
                bw[ni] = __builtin_bit_cast(bf16x8,
                    *(const ushort8*)(&Bb[(wn + ni * 16 + l15) * 64 + rchunk]));
#pragma unroll
            for (int mi = 0; mi < 4; ++mi)
#pragma unroll
                for (int ni = 0; ni < 4; ++ni)
                    acc[mi][ni] = __builtin_amdgcn_mfma_f32_16x16x32_bf16(af[mi], bw[ni], acc[mi][ni], 0, 0, 0);
        }
    }
    __syncthreads();   // LDS reusable for epilogue staging

    if (z == 3) {
#pragma unroll
        for (int ni = 0; ni < 4; ++ni) {
            const int col = bn + wn + ni * 16 + l15;
            const float bv = bias[col];
#pragma unroll
            for (int mi = 0; mi < 4; ++mi) {
                const int row = bm + wm + mi * 16 + lhi * 4;
#pragma unroll
                for (int r = 0; r < 4; ++r)
                    Cout[(size_t)(row + r) * 1024 + col] = acc[mi][ni][r] + bv;
            }
        }
        return;
    }

    unsigned short* stg = ((wid & 2) ? &Bs[0][0] : &As[0][0]) + (wid & 1) * 4096;
    const int h = (bn + wn) >> 6;

    if (z == 2) {
        // V^T with key-perm pi: sl -> 32*(mi>>1) + lhi*8 + 2r + (mi&1),
        // then s-chunk XOR by (d&7) at store.
        float biasv[4];
#pragma unroll
        for (int ni = 0; ni < 4; ++ni) biasv[ni] = bias[bn + wn + ni * 16 + l15];
#pragma unroll
        for (int mi = 0; mi < 4; ++mi)
#pragma unroll
            for (int ni = 0; ni < 4; ++ni)
#pragma unroll
                for (int r = 0; r < 4; ++r)
                    stg[(ni * 16 + l15) * 64 + 32 * (mi >> 1) + lhi * 8 + 2 * r + (mi & 1)] =
                        f2bf(acc[mi][ni][r] + biasv[ni]);
        __builtin_amdgcn_s_waitcnt(0);
        const int srow0 = bm + wm;
        const int b = srow0 >> 11, sbase = srow0 & 2047;
#pragma unroll
        for (int i = 0; i < 8; ++i) {
            const int dl = i * 8 + (lane >> 3);
            const ushort8 v = *(const ushort8*)(&stg[dl * 64 + (((lane & 7) ^ (dl & 7)) * 8)]);
            *(ushort8*)(&vt[((size_t)((b * 16 + h) * 64 + dl)) * 2048 + sbase + (lane & 7) * 8]) = v;
        }
        return;
    }

    // z == 0/1: per-head LayerNorm over the wave's 64 cols (one head)
    const float* g  = (z == 0) ? ln_g0 : ln_g1;
    const float* bb = (z == 0) ? ln_b0 : ln_b1;
    unsigned short* outp = (z == 0) ? qn : kn;
    const float scale = (z == 0) ? 0.125f * LOG2E : 1.0f;
    const int sxor = (z == 1) ? 7 : 0;   // K global gets d-chunk XOR by (s&7)
    float gv[4], bbv[4], biasv[4];
#pragma unroll
    for (int ni = 0; ni < 4; ++ni) {
        const int d = ni * 16 + l15;
        gv[ni] = g[d]; bbv[ni] = bb[d]; biasv[ni] = bias[bn + wn + d];
    }
#pragma unroll
    for (int mi = 0; mi < 4; ++mi) {
#pragma unroll
        for (int r = 0; r < 4; ++r) {
            float x0 = acc[mi][0][r] + biasv[0];
            float x1 = acc[mi][1][r] + biasv[1];
            float x2 = acc[mi][2][r] + biasv[2];
            float x3 = acc[mi][3][r] + biasv[3];
            float sum = (x0 + x1) + (x2 + x3);
#pragma unroll
            for (int off = 1; off < 16; off <<= 1) sum += __shfl_xor(sum, off);
            const float mean = sum * (1.f / 64.f);
            const float d0 = x0 - mean, d1 = x1 - mean, d2 = x2 - mean, d3 = x3 - mean;
            float vs = (d0 * d0 + d1 * d1) + (d2 * d2 + d3 * d3);
#pragma unroll
            for (int off = 1; off < 16; off <<= 1) vs += __shfl_xor(vs, off);
            const float rstd = rsqrtf(vs * (1.f / 64.f) + 1e-5f);
            const int rl = mi * 16 + lhi * 4 + r;
            stg[rl * 64 +  0 + l15] = f2bf((d0 * rstd * gv[0] + bbv[0]) * scale);
            stg[rl * 64 + 16 + l15] = f2bf((d1 * rstd * gv[1] + bbv[1]) * scale);
            stg[rl * 64 + 32 + l15] = f2bf((d2 * rstd * gv[2] + bbv[2]) * scale);
            stg[rl * 64 + 48 + l15] = f2bf((d3 * rstd * gv[3] + bbv[3]) * scale);
        }
    }
    __builtin_amdgcn_s_waitcnt(0);
#pragma unroll
    for (int i = 0; i < 8; ++i) {
        const int rl  = i * 8 + (lane >> 3);
        const int srow = bm + wm + rl;
        const int b = srow >> 11, s = srow & 2047;
        const ushort8 v = *(const ushort8*)(&stg[rl * 64 + (((lane & 7) ^ (rl & sxor)) * 8)]);
        *(ushort8*)(&outp[((size_t)((b * 16 + h) * 2048 + s)) * 64 + (lane & 7) * 8]) = v;
    }
}

// ---------------------------------------------------------------------------
// Output-projection GEMM: C[M,N] = A[M,K] * W[N,K]^T + bias, fp32 out.
// R14: BM=64, BN=64 -> grid (64,16) = 1024 blocks = 4 blocks/CU (was 512 = 2;
// gemm_out ran ~11us vs ~4.5us HBM floor -- same starved shape class R8
// fixed). LDS 32 KiB (2x8K As + 2x8K Bs). 4 waves, 2x2 of 32x32, acc[2][2].
// Pure parameter shrink of the R10-verified dbuf structure; x-major grid
// keeps id%8 == m-tile%8 (per-XCD A-slice L2-resident).
// ---------------------------------------------------------------------------
__global__ __launch_bounds__(256) void gemm_out(
    const unsigned short* __restrict__ A,
    const unsigned short* __restrict__ W,
    const float* __restrict__ bias,
    float* __restrict__ Cout)
{
    const int bm = blockIdx.x * 64;
    const int bn = blockIdx.y * 64;

    __shared__ unsigned short As[2][64 * 64];
    __shared__ unsigned short Bs[2][64 * 64];

    const int t    = threadIdx.x;
    const int lane = t & 63;
    const int wid  = t >> 6;
    const int l15  = lane & 15;
    const int lhi  = lane >> 4;
    const int wm   = (wid >> 1) * 32;
    const int wn   = (wid & 1) * 32;

    const int schunk = (lane & 7) ^ ((lane >> 3) & 7);
    const unsigned short* Ag = A + (size_t)(bm + (lane >> 3)) * 1024 + schunk * 8;
    const unsigned short* Wg = W + (size_t)(bn + (lane >> 3)) * 1024 + schunk * 8;

    f32x4 acc[2][2];
#pragma unroll
    for (int i = 0; i < 2; ++i)
#pragma unroll
        for (int j = 0; j < 2; ++j) acc[i][j] = (f32x4)0.f;

    // prologue: stage tile 0 into buf 0 (8 chunks each of As/Bs, 2 per wave)
#pragma unroll
    for (int c = 0; c < 2; ++c) {
        const int ch = wid * 2 + c;
        gload_lds16(Ag + (size_t)ch * 8 * 1024, &As[0][ch * 512]);
        gload_lds16(Wg + (size_t)ch * 8 * 1024, &Bs[0][ch * 512]);
    }

#pragma unroll 2
    for (int it = 0; it < 16; ++it) {
        __syncthreads();                      // tile it staged everywhere
        if (it < 15) {
            const int kt = (it + 1) * 64;
#pragma unroll
            for (int c = 0; c < 2; ++c) {
                const int ch = wid * 2 + c;
                gload_lds16(Ag + (size_t)ch * 8 * 1024 + kt, &As[(it + 1) & 1][ch * 512]);
                gload_lds16(Wg + (size_t)ch * 8 * 1024 + kt, &Bs[(it + 1) & 1][ch * 512]);
            }
        }
        const unsigned short* Ab = &As[it & 1][0];
        const unsigned short* Bb = &Bs[it & 1][0];
#pragma unroll
        for (int kk = 0; kk < 2; ++kk) {
            const int rchunk = ((kk * 4 + lhi) ^ (l15 & 7)) * 8;
            bf16x8 af[2], bw[2];
#pragma unroll
            for (int mi = 0; mi < 2; ++mi)
                af[mi] = __builtin_bit_cast(bf16x8,
                    *(const ushort8*)(&Ab[(wm + mi * 16 + l15) * 64 + rchunk]));
#pragma unroll
            for (int ni = 0; ni < 2; ++ni)
                bw[ni] = __builtin_bit_cast(bf16x8,
                    *(const ushort8*)(&Bb[(wn + ni * 16 + l15) * 64 + rchunk]));
#pragma unroll
            for (int mi = 0; mi < 2; ++mi)
#pragma unroll
                for (int ni = 0; ni < 2; ++ni)
                    acc[mi][ni] = __builtin_amdgcn_mfma_f32_16x16x32_bf16(af[mi], bw[ni], acc[mi][ni], 0, 0, 0);
        }
    }

#pragma unroll
    for (int ni = 0; ni < 2; ++ni) {
        const int col = bn + wn + ni * 16 + l15;
        const float bv = bias[col];
#pragma unroll
        for (int mi = 0; mi < 2; ++mi) {
            const int row = bm + wm + mi * 16 + lhi * 4;
#pragma unroll
            for (int r = 0; r < 4; ++r)
                Cout[(size_t)(row + r) * 1024 + col] = acc[mi][ni][r] + bv;
        }
    }
}

// ---------------------------------------------------------------------------
// Flash attention. 128 q rows/block, 8 waves x 16 rows, KV tiles of 64.
// 4-buffer statically-indexed counted-vmcnt pipeline, ONE barrier per tile
// (harness-verified structure, R1/R4/R8-R13):
//   iter t: [DMA(t+2); SM(t); vmcnt(2)+barrier; QK(t+1); PV(t)]
// Grid is (bh, qblock) so linear id%8 == bh%8: all 16 q-blocks of a head land
// on one XCD -> K/V (512KB/head, 4 heads/XCD = 2MB) stays L2-resident.
// Softmax sub folded into MFMA C-init: sacc = mfma(a,b, mneg).
// ---------------------------------------------------------------------------
__global__ __launch_bounds__(512, 4) void attn(
    const unsigned short* __restrict__ qn, const unsigned short* __restrict__ kn,
    const unsigned short* __restrict__ vt, unsigned short* __restrict__ o)
{
    __shared__ unsigned short Ks[4][64 * 64];
    __shared__ unsigned short Vs[4][64 * 64];
    __shared__ unsigned short Ps[128 * 64];

    const int tid  = threadIdx.x;
    const int lane = tid & 63;
    const int w    = tid >> 6;
    const int l15  = lane & 15;
    const int lhi  = lane >> 4;

    const int bh = blockIdx.x;          // b*16 + h  (x-major -> same-head co-XCD)
    const int q0 = blockIdx.y * 128;

    const unsigned short* qrp = qn + ((size_t)bh * SEQ + q0 + w * 16 + l15) * 64 + lhi * 8;
    const bf16x8 aq0 = __builtin_bit_cast(bf16x8, *(const ushort8*)(qrp));
    const bf16x8 aq1 = __builtin_bit_cast(bf16x8, *(const ushort8*)(qrp + 32));

    // DMA staging: wave w covers rows w*8..w*8+7; lane: row w*8+(lane>>3), chunk lane&7
    const unsigned short* kg = kn + ((size_t)bh * SEQ + w * 8 + (lane >> 3)) * 64 + (lane & 7) * 8;
    const unsigned short* vg = vt + ((size_t)bh * 64 + w * 8 + (lane >> 3)) * 2048 + (lane & 7) * 8;

    f32x4 oacc[4];
#pragma unroll
    for (int nd = 0; nd < 4; ++nd) oacc[nd] = (f32x4)0.f;
    float l_part[4];
#pragma unroll
    for (int i = 0; i < 4; ++i) l_part[i] = 0.f;
    f32x4 mneg = (f32x4)100.f;          // -m_run; m_run starts at -100 (finite)

    f32x4 sacc[4];

    auto QK = [&](const unsigned short* kb) {
        __builtin_amdgcn_s_setprio(1);
#pragma unroll
        for (int ni = 0; ni < 4; ++ni) {
            const int krow = ni * 16 + l15;
            const bf16x8 bk = __builtin_bit_cast(bf16x8,
                *(const ushort8*)(&kb[krow * 64 + ((lhi ^ (krow & 7)) * 8)]));
            sacc[ni] = __builtin_amdgcn_mfma_f32_16x16x32_bf16(aq0, bk, mneg, 0, 0, 0);
        }
#pragma unroll
        for (int ni = 0; ni < 4; ++ni) {
            const int krow = ni * 16 + l15;
            const bf16x8 bk = __builtin_bit_cast(bf16x8,
                *(const ushort8*)(&kb[krow * 64 + (((4 + lhi) ^ (krow & 7)) * 8)]));
            sacc[ni] = __builtin_amdgcn_mfma_f32_16x16x32_bf16(aq1, bk, sacc[ni], 0, 0, 0);
        }
        __builtin_amdgcn_s_setprio(0);
    };

    // prologue: stage tiles 0 and 1, wait tile 0, compute QK(0)
    gload_lds16(kg,                    &Ks[0][w * 512]);
    gload_lds16(vg,                    &Vs[0][w * 512]);
    gload_lds16(kg + (size_t)64 * 64,  &Ks[1][w * 512]);
    gload_lds16(vg + 64,               &Vs[1][w * 512]);
    __builtin_amdgcn_sched_barrier(0);
    asm volatile("s_waitcnt vmcnt(2)" ::: "memory");
    asm volatile("s_barrier" ::: "memory");
    QK(&Ks[0][0]);

#pragma unroll 4
    for (int t = 0; t < 32; ++t) {
        // issue DMA for tile t+2 into buf (t+2)&3 (statically indexed)
        if (t < 30) {
            gload_lds16(kg + (size_t)(t + 2) * 64 * 64, &Ks[(t + 2) & 3][w * 512]);
            gload_lds16(vg + (t + 2) * 64,              &Vs[(t + 2) & 3][w * 512]);
        }
        __builtin_amdgcn_sched_barrier(0);

        // SM(t): sacc already holds s - m_run (C-init bias); defer-max softmax
        float tmax[4];
#pragma unroll
        for (int r = 0; r < 4; ++r)
            tmax[r] = fmaxf(fmaxf(fmaxf(sacc[0][r], sacc[1][r]), sacc[2][r]), sacc[3][r]);
        const float dmax = fmaxf(fmaxf(fmaxf(tmax[0], tmax[1]), tmax[2]), tmax[3]);
        if (!__all(dmax <= 8.0f)) {          // rare: rescale path
#pragma unroll
            for (int r = 0; r < 4; ++r) {
                float tm = tmax[r];
#pragma unroll
                for (int off = 1; off < 16; off <<= 1) tm = fmaxf(tm, __shfl_xor(tm, off));
                const float delta = fmaxf(tm, 0.f);      // m_new - m_old
                const float alpha = __builtin_amdgcn_exp2f(-delta);
                mneg[r] -= delta;
                l_part[r] *= alpha;
#pragma unroll
                for (int nd = 0; nd < 4; ++nd) oacc[nd][r] *= alpha;
#pragma unroll
                for (int ni = 0; ni < 4; ++ni) sacc[ni][r] -= delta;
            }
        }
#pragma unroll
        for (int r = 0; r < 4; ++r) {
            const float p0 = __builtin_amdgcn_exp2f(sacc[0][r]);
            const float p1 = __builtin_amdgcn_exp2f(sacc[1][r]);
            const float p2 = __builtin_amdgcn_exp2f(sacc[2][r]);
            const float p3 = __builtin_amdgcn_exp2f(sacc[3][r]);
            l_part[r] += (p0 + p1) + (p2 + p3);
            unsigned int pk0, pk1;
            asm("v_cvt_pk_bf16_f32 %0, %1, %2" : "=v"(pk0) : "v"(p0), "v"(p1));
            asm("v_cvt_pk_bf16_f32 %0, %1, %2" : "=v"(pk1) : "v"(p2), "v"(p3));
            const int prow = w * 16 + lhi * 4 + r;
            const int rs7  = prow & 7;
            *(unsigned int*)(&Ps[prow * 64 + (((l15 >> 2) ^ rs7) * 8) + 2 * (l15 & 3)]) = pk0;
            *(unsigned int*)(&Ps[prow * 64 + (((4 + (l15 >> 2)) ^ rs7) * 8) + 2 * (l15 & 3)]) = pk1;
        }

        // QK(t+1): hoisted between Ps writes and Ps reads (single barrier/tile)
        if (t < 31) {
            if (t < 30) { asm volatile("s_waitcnt vmcnt(2)" ::: "memory"); }
            else        { asm volatile("s_waitcnt vmcnt(0)" ::: "memory"); }
            asm volatile("s_barrier" ::: "memory");   // tile t+1 staged everywhere
            QK(&Ks[(t + 1) & 3][0]);
        }

        // PV(t)
        __builtin_amdgcn_s_setprio(1);
#pragma unroll
        for (int kk = 0; kk < 2; ++kk) {
            const int arow = w * 16 + l15;
            const bf16x8 ap = __builtin_bit_cast(bf16x8,
                *(const ushort8*)(&Ps[arow * 64 + (((kk * 4 + lhi) ^ (arow & 7)) * 8)]));
#pragma unroll
            for (int nd = 0; nd < 4; ++nd) {
                const int vrow = nd * 16 + l15;
                const bf16x8 bv = __builtin_bit_cast(bf16x8,
                    *(const ushort8*)(&Vs[t & 3][vrow * 64 + (((kk * 4 + lhi) ^ (vrow & 7)) * 8)]));
                oacc[nd] = __builtin_amdgcn_mfma_f32_16x16x32_bf16(ap, bv, oacc[nd], 0, 0, 0);
            }
        }
        __builtin_amdgcn_s_setprio(0);
    }

    // epilogue: reduce l, O/l, bf16 out [B,S,H,64]
    const int b = bh >> 4, h = bh & 15;
#pragma unroll
    for (int r = 0; r < 4; ++r) {
        float ls = l_part[r];
#pragma unroll
        for (int off = 1; off < 16; off <<= 1) ls += __shfl_xor(ls, off);
        const float inv = 1.f / ls;
        const int qrow = q0 + w * 16 + lhi * 4 + r;
        const size_t base = ((size_t)(b * SEQ + qrow) * 16 + h) * 64;
#pragma unroll
        for (int nd = 0; nd < 4; ++nd)
            o[base + nd * 16 + l15] = f2bf(oacc[nd][r] * inv);
    }
}

// ---------------------------------------------------------------------------
extern "C" void kernel_launch(void* const* d_in, const int* in_sizes, int n_in,
                              void* d_out, int out_size, void* d_ws, size_t ws_size,
                              hipStream_t stream)
{
    const float* query  = (const float*)d_in[0];
    const float* q_w    = (const float*)d_in[1];
    const float* q_b    = (const float*)d_in[2];
    const float* k_w    = (const float*)d_in[3];
    const float* k_b    = (const float*)d_in[4];
    const float* v_w    = (const float*)d_in[5];
    const float* v_b    = (const float*)d_in[6];
    const float* o_w    = (const float*)d_in[7];
    const float* o_b    = (const float*)d_in[8];
    const float* q_ln_g = (const float*)d_in[9];
    const float* q_ln_b = (const float*)d_in[10];
    const float* k_ln_g = (const float*)d_in[11];
    const float* k_ln_b = (const float*)d_in[12];

    char* ws = (char*)d_ws;
    unsigned short* qbf = (unsigned short*)(ws);                   // 8 MB
    unsigned short* wq  = (unsigned short*)(ws + (8ull  << 20));   // 2 MB
    unsigned short* wk  = (unsigned short*)(ws + (10ull << 20));   // 2 MB
    unsigned short* wv  = (unsigned short*)(ws + (12ull << 20));   // 2 MB
    unsigned short* wo  = (unsigned short*)(ws + (14ull << 20));   // 2 MB
    unsigned short* qnb = (unsigned short*)(ws + (16ull << 20));   // 8 MB
    unsigned short* knb = (unsigned short*)(ws + (24ull << 20));   // 8 MB
    unsigned short* vtb = (unsigned short*)(ws + (32ull << 20));   // 8 MB
    unsigned short* ofb = (unsigned short*)(ws + (40ull << 20));   // 8 MB

    conv_bf16<<<dim3(2048, 5), 256, 0, stream>>>(query, q_w, k_w, v_w, o_w,
                                                 qbf, wq, wk, wv, wo);

    dim3 g1(32, 8, 3);
    gemm_bf16<<<g1, 256, 0, stream>>>(qbf, wq, wk, wv, q_b, k_b, v_b,
                                      q_ln_g, q_ln_b, k_ln_g, k_ln_b,
                                      qnb, knb, vtb, nullptr, -1);

    dim3 g3(32, 16);
    attn<<<g3, 512, 0, stream>>>(qnb, knb, vtb, ofb);

    dim3 g4(64, 16);
    gemm_out<<<g4, 256, 0, stream>>>(ofb, wo, o_b, (float*)d_out);
}